// Round 6
// baseline (266.457 us; speedup 1.0000x reference)
//
#include <hip/hip_runtime.h>

// Problem constants (fixed by the reference setup)
constexpr int N_IN  = 50000;
constexpr int C     = 64;
constexpr int T     = 8;
constexpr int E     = 800000;
constexpr int N_OUT = 50000;
constexpr int F     = 64;

// ---------------------------------------------------------------------------
// Workspace layout (bytes); total ~22.8 MB (ws >= 102.4 MB proven round 2)
// ---------------------------------------------------------------------------
constexpr size_t OFF_NFBF = 0;                     // bf16 [N_IN][64]     6.4 MB
constexpr size_t OFF_KT   = 6400000;               // bf16 [64][512]      64 KB
constexpr size_t OFF_CNT  = OFF_KT + 65536;        // int  [N_OUT+1]      (-> start[])
constexpr size_t OFF_CUR  = OFF_CNT + 200064;      // int  [N_OUT]
constexpr size_t OFF_BSUM = OFF_CUR + 200064;      // int  [256]
constexpr size_t OFF_ISRT = OFF_BSUM + 1024;       // int  [E]            3.2 MB
constexpr size_t OFF_WSRT = OFF_ISRT + 3200000;    // uint4[E] bf16 w     12.8 MB

typedef __attribute__((ext_vector_type(8))) short short8;
typedef __attribute__((ext_vector_type(4))) float f32x4;

__device__ inline unsigned short f2bf(float x) {  // fp32 -> bf16, RNE
    unsigned int u = __float_as_uint(x);
    unsigned int r = (u + 0x7FFFu + ((u >> 16) & 1u)) >> 16;
    return (unsigned short)r;
}
__device__ inline float bf2f(unsigned short u) {
    return __uint_as_float(((unsigned int)u) << 16);
}
__device__ inline unsigned int pk2(float a, float b) {  // {lo=a, hi=b} bf16x2
    return (unsigned int)f2bf(a) | ((unsigned int)f2bf(b) << 16);
}

// ---------------------------------------------------------------------------
// Fused prep: [0,3125) nf->bf16 | [3125,3157) K transpose | [3157,6282) hist
// ---------------------------------------------------------------------------
constexpr int NF_BLOCKS   = N_IN * C / 4 / 256;  // 3125 (exact)
constexpr int KT_BLOCKS   = 32;
constexpr int HIST_BLOCKS = E / 256;             // 3125 (exact)

__global__ __launch_bounds__(256) void prep_kernel(const float* __restrict__ nf,
                                                   const float* __restrict__ Kmat,
                                                   const int* __restrict__ idx,
                                                   unsigned short* __restrict__ nf_bf,
                                                   unsigned short* __restrict__ K_T,
                                                   int* __restrict__ cnt) {
    const int b   = blockIdx.x;
    const int tid = threadIdx.x;

    if (b < NF_BLOCKS) {
        int i = b * 256 + tid;  // float4 units; 800000 exact
        float4 v = ((const float4*)nf)[i];
        ((uint2*)nf_bf)[i] = make_uint2(pk2(v.x, v.y), pk2(v.z, v.w));
    } else if (b < NF_BLOCKS + KT_BLOCKS) {
        for (int k = (b - NF_BLOCKS) * 256 + tid; k < T * C * F; k += KT_BLOCKS * 256) {
            int f = k & 63;
            int c = (k >> 6) & 63;
            int t = k >> 12;
            K_T[f * 512 + t * 64 + c] = f2bf(Kmat[k]);
        }
    } else {
        int e = (b - NF_BLOCKS - KT_BLOCKS) * 256 + tid;  // 800000 exact
        atomicAdd(&cnt[idx[2 * e]], 1);
    }
}

// ---------------------------------------------------------------------------
// Scan pass A: per-256-chunk exclusive scan in place, chunk totals -> bsum
// ---------------------------------------------------------------------------
__global__ __launch_bounds__(256) void scanA_kernel(int* __restrict__ cnt,
                                                    int* __restrict__ bsum) {
    __shared__ int sh[256];
    const int tid = threadIdx.x;
    int g = blockIdx.x * 256 + tid;
    int v = (g < N_OUT) ? cnt[g] : 0;
    sh[tid] = v;
    __syncthreads();
#pragma unroll
    for (int off = 1; off < 256; off <<= 1) {
        int x = 0;
        if (tid >= off) x = sh[tid - off];
        __syncthreads();
        if (tid >= off) sh[tid] += x;
        __syncthreads();
    }
    int incl = sh[tid];
    if (g < N_OUT) cnt[g] = incl - v;
    if (tid == 255) bsum[blockIdx.x] = incl;
}

// ---------------------------------------------------------------------------
// Scan pass BC: each block adds sum(bsum[0..bi)) to its chunk; init cursor.
// ---------------------------------------------------------------------------
__global__ __launch_bounds__(256) void scanBC_kernel(int* __restrict__ cnt,
                                                     const int* __restrict__ bsum,
                                                     int* __restrict__ cursor) {
    __shared__ int sh[256];
    const int bi  = blockIdx.x;
    const int tid = threadIdx.x;
    sh[tid] = (tid < bi) ? bsum[tid] : 0;  // nchunks(196) < 256
    __syncthreads();
#pragma unroll
    for (int off = 128; off >= 1; off >>= 1) {
        if (tid < off) sh[tid] += sh[tid + off];
        __syncthreads();
    }
    const int offset = sh[0];
    int g = bi * 256 + tid;
    if (g < N_OUT) {
        int s = cnt[g] + offset;
        cnt[g] = s;
        cursor[g] = s;
    }
    if (bi == 0 && tid == 0) cnt[N_OUT] = E;
}

// ---------------------------------------------------------------------------
// Scatter: 4 edges per thread. 4 independent cursor atomics + 4 independent
// 16 B record stores in flight (was 1 -> latency-bound at VALUBusy 0.7%).
// Weights packed to bf16x8 (uint4) -> halves the random-write bytes.
// ---------------------------------------------------------------------------
__global__ __launch_bounds__(256) void scatter_kernel(const int* __restrict__ idx,
                                                      const float* __restrict__ ef,
                                                      int* __restrict__ cursor,
                                                      int* __restrict__ isorted,
                                                      uint4* __restrict__ wsorted) {
    const int base = (blockIdx.x * 256 + threadIdx.x) * 4;
    if (base >= E) return;  // E % 4 == 0, so base < E implies base+4 <= E

    // 4 edges' {o,i} pairs: 8 ints = 2 x int4, coalesced
    int4 a = ((const int4*)idx)[base / 2];      // {o0,i0,o1,i1}
    int4 b = ((const int4*)idx)[base / 2 + 1];  // {o2,i2,o3,i3}

    // 4 independent atomics in flight
    int p0 = atomicAdd(&cursor[a.x], 1);
    int p1 = atomicAdd(&cursor[a.z], 1);
    int p2 = atomicAdd(&cursor[b.x], 1);
    int p3 = atomicAdd(&cursor[b.z], 1);

    // weights: for each t, 4 consecutive edges = one float4 (coalesced)
    float4 w[8];
#pragma unroll
    for (int t = 0; t < T; ++t) w[t] = *(const float4*)(ef + (size_t)t * E + base);
    const float* wf = (const float*)w;  // wf[t*4 + k] = ef[t][base+k]

    const int pos[4]  = {p0, p1, p2, p3};
    const int iin[4]  = {a.y, a.w, b.y, b.w};
#pragma unroll
    for (int k = 0; k < 4; ++k) {
        uint4 r;
        r.x = pk2(wf[0 * 4 + k], wf[1 * 4 + k]);
        r.y = pk2(wf[2 * 4 + k], wf[3 * 4 + k]);
        r.z = pk2(wf[4 * 4 + k], wf[5 * 4 + k]);
        r.w = pk2(wf[6 * 4 + k], wf[7 * 4 + k]);
        isorted[pos[k]] = iin[k];
        wsorted[pos[k]] = r;
    }
}

// ---------------------------------------------------------------------------
// Aggregate: block = 16 waves (1024 thr) = 16 output nodes, ONE node per wave
// (removes the 4-node serial chain; 50000 waves of TLP).
//  Phase 1 (per wave, lane=c): per 64-edge chunk, coalesced preload of
//    isorted -> registers and wsorted -> LDS; 8-edge unroll = 8 independent
//    128 B nf gathers in flight; weights via ds_read_b128 broadcast.
//  Phase 2 (waves 0-3): out_tile(16x64) = A(16x512) @ K_T^T via MFMA.
// ---------------------------------------------------------------------------
__global__ __launch_bounds__(1024) void aggregate_kernel(const unsigned short* __restrict__ nf_bf,
                                                         const unsigned short* __restrict__ K_T,
                                                         const int* __restrict__ start,
                                                         const int* __restrict__ isorted,
                                                         const uint4* __restrict__ wsorted,
                                                         const float* __restrict__ bias,
                                                         float* __restrict__ out) {
    __shared__ unsigned short A_lds[16][520];  // +8 pad
    __shared__ uint4 W_lds[16][64];            // per-wave weight staging (16 KB)

    const int wave = threadIdx.x >> 6;
    const int lane = threadIdx.x & 63;
    const int node_base = blockIdx.x * 16;  // 50000 = 3125*16 exact
    const int o = node_base + wave;

    const int s0 = __builtin_amdgcn_readfirstlane(start[o]);
    const int s1 = __builtin_amdgcn_readfirstlane(start[o + 1]);

    float acc[8] = {0.f, 0.f, 0.f, 0.f, 0.f, 0.f, 0.f, 0.f};

    for (int base = s0; base < s1; base += 64) {
        const int cnt = min(64, s1 - base);
        int iv = 0;
        if (base + lane < s1) {
            iv = isorted[base + lane];              // coalesced 4 B
            W_lds[wave][lane] = wsorted[base + lane];  // coalesced 16 B
        }
        // W_lds[wave] is private to this wave: no barrier needed (lgkmcnt only)

        int j = 0;
        for (; j + 8 <= cnt; j += 8) {
            int ii[8];
#pragma unroll
            for (int k = 0; k < 8; ++k) ii[k] = __builtin_amdgcn_readlane(iv, j + k);
            float x[8];
#pragma unroll
            for (int k = 0; k < 8; ++k)  // 8 independent 128 B gathers
                x[k] = bf2f(nf_bf[(size_t)ii[k] * 64 + lane]);
#pragma unroll
            for (int k = 0; k < 8; ++k) {
                uint4 wq = W_lds[wave][j + k];  // uniform addr -> broadcast b128
                acc[0] += __uint_as_float(wq.x << 16) * x[k];
                acc[1] += __uint_as_float(wq.x & 0xFFFF0000u) * x[k];
                acc[2] += __uint_as_float(wq.y << 16) * x[k];
                acc[3] += __uint_as_float(wq.y & 0xFFFF0000u) * x[k];
                acc[4] += __uint_as_float(wq.z << 16) * x[k];
                acc[5] += __uint_as_float(wq.z & 0xFFFF0000u) * x[k];
                acc[6] += __uint_as_float(wq.w << 16) * x[k];
                acc[7] += __uint_as_float(wq.w & 0xFFFF0000u) * x[k];
            }
        }
        for (; j < cnt; ++j) {
            const int i0 = __builtin_amdgcn_readlane(iv, j);
            float x0 = bf2f(nf_bf[(size_t)i0 * 64 + lane]);
            uint4 wq = W_lds[wave][j];
            acc[0] += __uint_as_float(wq.x << 16) * x0;
            acc[1] += __uint_as_float(wq.x & 0xFFFF0000u) * x0;
            acc[2] += __uint_as_float(wq.y << 16) * x0;
            acc[3] += __uint_as_float(wq.y & 0xFFFF0000u) * x0;
            acc[4] += __uint_as_float(wq.z << 16) * x0;
            acc[5] += __uint_as_float(wq.z & 0xFFFF0000u) * x0;
            acc[6] += __uint_as_float(wq.w << 16) * x0;
            acc[7] += __uint_as_float(wq.w & 0xFFFF0000u) * x0;
        }
    }

#pragma unroll
    for (int t = 0; t < T; ++t) A_lds[wave][t * 64 + lane] = f2bf(acc[t]);
    __syncthreads();

    // ---- Phase 2: waves 0-3 each handle one 16-col f-tile ----
    if (wave < 4) {
        const int mrow = lane & 15;
        const int kb   = lane >> 4;
        const int fcol = wave * 16 + mrow;

        f32x4 acc4 = {0.f, 0.f, 0.f, 0.f};
#pragma unroll
        for (int s = 0; s < 16; ++s) {
            const int k0 = s * 32 + kb * 8;
            short8 av = *(const short8*)&A_lds[mrow][k0];
            short8 bv = *(const short8*)(K_T + (size_t)fcol * 512 + k0);
            acc4 = __builtin_amdgcn_mfma_f32_16x16x32_bf16(av, bv, acc4, 0, 0, 0);
        }

        const float bb = bias[fcol];
#pragma unroll
        for (int r = 0; r < 4; ++r) {
            const int m = kb * 4 + r;
            out[(size_t)(node_base + m) * F + fcol] = acc4[r] + bb;
        }
    }
}

// ---------------------------------------------------------------------------
extern "C" void kernel_launch(void* const* d_in, const int* in_sizes, int n_in,
                              void* d_out, int out_size, void* d_ws, size_t ws_size,
                              hipStream_t stream) {
    const float* nf   = (const float*)d_in[0];  // (N_IN, C)
    const float* ef   = (const float*)d_in[1];  // (T, E)
    const int*   idx  = (const int*)d_in[2];    // (E, 2) int32 on device
    const float* Kmat = (const float*)d_in[3];  // (T, C, F)
    const float* bias = (const float*)d_in[4];  // (F,)
    float*       out  = (float*)d_out;          // (N_OUT, F)

    char* ws = (char*)d_ws;
    unsigned short* nf_bf   = (unsigned short*)(ws + OFF_NFBF);
    unsigned short* K_T     = (unsigned short*)(ws + OFF_KT);
    int*            cnt     = (int*)(ws + OFF_CNT);  // becomes start[]
    int*            cursor  = (int*)(ws + OFF_CUR);
    int*            bsum    = (int*)(ws + OFF_BSUM);
    int*            isorted = (int*)(ws + OFF_ISRT);
    uint4*          wsorted = (uint4*)(ws + OFF_WSRT);

    const int nchunks = (N_OUT + 255) / 256;  // 196

    hipMemsetAsync(cnt, 0, (N_OUT + 1) * sizeof(int), stream);
    prep_kernel<<<NF_BLOCKS + KT_BLOCKS + HIST_BLOCKS, 256, 0, stream>>>(
        nf, Kmat, idx, nf_bf, K_T, cnt);
    scanA_kernel<<<nchunks, 256, 0, stream>>>(cnt, bsum);
    scanBC_kernel<<<nchunks, 256, 0, stream>>>(cnt, bsum, cursor);
    scatter_kernel<<<(E / 4 + 255) / 256, 256, 0, stream>>>(idx, ef, cursor, isorted, wsorted);
    aggregate_kernel<<<N_OUT / 16, 1024, 0, stream>>>(
        nf_bf, K_T, cnt, isorted, wsorted, bias, out);
}

// Round 7
// 237.055 us; speedup vs baseline: 1.1240x; 1.1240x over previous
//
#include <hip/hip_runtime.h>

// Problem constants (fixed by the reference setup)
constexpr int N_IN  = 50000;
constexpr int C     = 64;
constexpr int T     = 8;
constexpr int E     = 800000;
constexpr int N_OUT = 50000;
constexpr int F     = 64;

// ---------------------------------------------------------------------------
// Workspace layout (bytes); total ~35.6 MB (ws >= 102.4 MB proven round 2)
// ---------------------------------------------------------------------------
constexpr size_t OFF_NFBF = 0;                     // bf16 [N_IN][64]     6.4 MB
constexpr size_t OFF_KT   = 6400000;               // bf16 [64][512]      64 KB
constexpr size_t OFF_CNT  = OFF_KT + 65536;        // int  [N_OUT+1]      (-> start[])
constexpr size_t OFF_CUR  = OFF_CNT + 200064;      // int  [N_OUT]
constexpr size_t OFF_BSUM = OFF_CUR + 200064;      // int  [256]
constexpr size_t OFF_ISRT = OFF_BSUM + 1024;       // int  [E]            3.2 MB
constexpr size_t OFF_WSRT = OFF_ISRT + 3200000;    // f32  [E][8]        25.6 MB

typedef __attribute__((ext_vector_type(8))) short short8;
typedef __attribute__((ext_vector_type(4))) float f32x4;

__device__ inline unsigned short f2bf(float x) {  // fp32 -> bf16, RNE
    unsigned int u = __float_as_uint(x);
    unsigned int r = (u + 0x7FFFu + ((u >> 16) & 1u)) >> 16;
    return (unsigned short)r;
}
__device__ inline float bf2f(unsigned short u) {
    return __uint_as_float(((unsigned int)u) << 16);
}
__device__ inline unsigned int pk2(float a, float b) {  // {lo=a, hi=b} bf16x2
    return (unsigned int)f2bf(a) | ((unsigned int)f2bf(b) << 16);
}

// ---------------------------------------------------------------------------
// Fused prep: [0,3125) nf->bf16 | [3125,3157) K transpose | [3157,6282) hist
// ---------------------------------------------------------------------------
constexpr int NF_BLOCKS   = N_IN * C / 4 / 256;  // 3125 (exact)
constexpr int KT_BLOCKS   = 32;
constexpr int HIST_BLOCKS = E / 256;             // 3125 (exact)

__global__ __launch_bounds__(256) void prep_kernel(const float* __restrict__ nf,
                                                   const float* __restrict__ Kmat,
                                                   const int* __restrict__ idx,
                                                   unsigned short* __restrict__ nf_bf,
                                                   unsigned short* __restrict__ K_T,
                                                   int* __restrict__ cnt) {
    const int b   = blockIdx.x;
    const int tid = threadIdx.x;

    if (b < NF_BLOCKS) {
        int i = b * 256 + tid;  // float4 units; 800000 exact
        float4 v = ((const float4*)nf)[i];
        ((uint2*)nf_bf)[i] = make_uint2(pk2(v.x, v.y), pk2(v.z, v.w));
    } else if (b < NF_BLOCKS + KT_BLOCKS) {
        for (int k = (b - NF_BLOCKS) * 256 + tid; k < T * C * F; k += KT_BLOCKS * 256) {
            int f = k & 63;
            int c = (k >> 6) & 63;
            int t = k >> 12;
            K_T[f * 512 + t * 64 + c] = f2bf(Kmat[k]);
        }
    } else {
        int e = (b - NF_BLOCKS - KT_BLOCKS) * 256 + tid;  // 800000 exact
        atomicAdd(&cnt[idx[2 * e]], 1);
    }
}

// ---------------------------------------------------------------------------
// Scan pass A: per-256-chunk exclusive scan in place, chunk totals -> bsum
// ---------------------------------------------------------------------------
__global__ __launch_bounds__(256) void scanA_kernel(int* __restrict__ cnt,
                                                    int* __restrict__ bsum) {
    __shared__ int sh[256];
    const int tid = threadIdx.x;
    int g = blockIdx.x * 256 + tid;
    int v = (g < N_OUT) ? cnt[g] : 0;
    sh[tid] = v;
    __syncthreads();
#pragma unroll
    for (int off = 1; off < 256; off <<= 1) {
        int x = 0;
        if (tid >= off) x = sh[tid - off];
        __syncthreads();
        if (tid >= off) sh[tid] += x;
        __syncthreads();
    }
    int incl = sh[tid];
    if (g < N_OUT) cnt[g] = incl - v;
    if (tid == 255) bsum[blockIdx.x] = incl;
}

// ---------------------------------------------------------------------------
// Scan pass BC: each block adds sum(bsum[0..bi)) to its chunk; init cursor.
// ---------------------------------------------------------------------------
__global__ __launch_bounds__(256) void scanBC_kernel(int* __restrict__ cnt,
                                                     const int* __restrict__ bsum,
                                                     int* __restrict__ cursor) {
    __shared__ int sh[256];
    const int bi  = blockIdx.x;
    const int tid = threadIdx.x;
    sh[tid] = (tid < bi) ? bsum[tid] : 0;  // nchunks(196) < 256
    __syncthreads();
#pragma unroll
    for (int off = 128; off >= 1; off >>= 1) {
        if (tid < off) sh[tid] += sh[tid + off];
        __syncthreads();
    }
    const int offset = sh[0];
    int g = bi * 256 + tid;
    if (g < N_OUT) {
        int s = cnt[g] + offset;
        cnt[g] = s;
        cursor[g] = s;
    }
    if (bi == 0 && tid == 0) cnt[N_OUT] = E;
}

// ---------------------------------------------------------------------------
// Scatter: 4 edges per thread (round-6 win: 4 independent atomics + record
// stores in flight; round-5 version was 1-deep and latency-bound at
// VALUBusy 0.7%). Weights stay fp32 (round-6's bf16 packing regressed the
// aggregate: per-lane VALU unpack >> the saved bytes).
// ---------------------------------------------------------------------------
__global__ __launch_bounds__(256) void scatter_kernel(const int* __restrict__ idx,
                                                      const float* __restrict__ ef,
                                                      int* __restrict__ cursor,
                                                      int* __restrict__ isorted,
                                                      float* __restrict__ wsorted) {
    const int base = (blockIdx.x * 256 + threadIdx.x) * 4;
    if (base >= E) return;  // E % 4 == 0

    int4 a = ((const int4*)idx)[base / 2];      // {o0,i0,o1,i1}
    int4 b = ((const int4*)idx)[base / 2 + 1];  // {o2,i2,o3,i3}

    int p0 = atomicAdd(&cursor[a.x], 1);
    int p1 = atomicAdd(&cursor[a.z], 1);
    int p2 = atomicAdd(&cursor[b.x], 1);
    int p3 = atomicAdd(&cursor[b.z], 1);

    float4 w[8];
#pragma unroll
    for (int t = 0; t < T; ++t) w[t] = *(const float4*)(ef + (size_t)t * E + base);
    const float* wf = (const float*)w;  // wf[t*4 + k] = ef[t][base+k]

    const int pos[4] = {p0, p1, p2, p3};
    const int iin[4] = {a.y, a.w, b.y, b.w};
#pragma unroll
    for (int k = 0; k < 4; ++k) {
        isorted[pos[k]] = iin[k];
        float4* dst = (float4*)(wsorted + (size_t)pos[k] * 8);
        dst[0] = make_float4(wf[0 * 4 + k], wf[1 * 4 + k], wf[2 * 4 + k], wf[3 * 4 + k]);
        dst[1] = make_float4(wf[4 * 4 + k], wf[5 * 4 + k], wf[6 * 4 + k], wf[7 * 4 + k]);
    }
}

// ---------------------------------------------------------------------------
// Aggregate (round-5 structure, the measured-best): block = 4 waves = 16
// output nodes; each wave does 4 nodes serially (lower barrier-imbalance
// variance than 1-node/wave x 16 waves).
//  Phase 1 (lane=c): coalesced preload of 64 isorted ids + readlane
//    broadcast; 4-edge unroll -> 4 independent 128 B nf gathers in flight;
//    weights via wave-uniform fp32 loads (s_load path, zero VALU).
//  Phase 2 (per wave, one 16-col f-tile): out = A(16x512) @ K_T^T via MFMA.
// ---------------------------------------------------------------------------
__global__ __launch_bounds__(256) void aggregate_kernel(const unsigned short* __restrict__ nf_bf,
                                                        const unsigned short* __restrict__ K_T,
                                                        const int* __restrict__ start,
                                                        const int* __restrict__ isorted,
                                                        const float* __restrict__ wsorted,
                                                        const float* __restrict__ bias,
                                                        float* __restrict__ out) {
    __shared__ unsigned short A_lds[16][520];  // +8 pad

    const int wave = threadIdx.x >> 6;
    const int lane = threadIdx.x & 63;
    const int node_base = blockIdx.x * 16;  // 50000 = 3125*16 exact

    // ---- Phase 1: segment aggregation ----
    for (int q = 0; q < 4; ++q) {
        const int m = wave * 4 + q;
        const int o = node_base + m;
        const int s0 = __builtin_amdgcn_readfirstlane(start[o]);
        const int s1 = __builtin_amdgcn_readfirstlane(start[o + 1]);

        float acc[8] = {0.f, 0.f, 0.f, 0.f, 0.f, 0.f, 0.f, 0.f};

        for (int base = s0; base < s1; base += 64) {
            const int cnt = min(64, s1 - base);
            int iv = (base + lane < s1) ? isorted[base + lane] : 0;

            int j = 0;
            for (; j + 4 <= cnt; j += 4) {
                const int i0 = __builtin_amdgcn_readlane(iv, j + 0);
                const int i1 = __builtin_amdgcn_readlane(iv, j + 1);
                const int i2 = __builtin_amdgcn_readlane(iv, j + 2);
                const int i3 = __builtin_amdgcn_readlane(iv, j + 3);
                // 4 independent 128 B gathers in flight
                float x0 = bf2f(nf_bf[(size_t)i0 * 64 + lane]);
                float x1 = bf2f(nf_bf[(size_t)i1 * 64 + lane]);
                float x2 = bf2f(nf_bf[(size_t)i2 * 64 + lane]);
                float x3 = bf2f(nf_bf[(size_t)i3 * 64 + lane]);
                // wave-uniform sequential weight loads (scalar path)
                const float* wp = wsorted +
                    (size_t)__builtin_amdgcn_readfirstlane(base + j) * 8;
#pragma unroll
                for (int t = 0; t < T; ++t) {
                    acc[t] += wp[t] * x0;
                    acc[t] += wp[8 + t] * x1;
                    acc[t] += wp[16 + t] * x2;
                    acc[t] += wp[24 + t] * x3;
                }
            }
            for (; j < cnt; ++j) {
                const int i0 = __builtin_amdgcn_readlane(iv, j);
                float x0 = bf2f(nf_bf[(size_t)i0 * 64 + lane]);
                const float* wp = wsorted +
                    (size_t)__builtin_amdgcn_readfirstlane(base + j) * 8;
#pragma unroll
                for (int t = 0; t < T; ++t) acc[t] += wp[t] * x0;
            }
        }

#pragma unroll
        for (int t = 0; t < T; ++t) A_lds[m][t * 64 + lane] = f2bf(acc[t]);
    }
    __syncthreads();

    // ---- Phase 2: MFMA epilogue; wave handles f-tile [wave*16, wave*16+16) ----
    const int mrow = lane & 15;
    const int kb   = lane >> 4;
    const int fcol = wave * 16 + mrow;

    f32x4 acc4 = {0.f, 0.f, 0.f, 0.f};
#pragma unroll
    for (int s = 0; s < 16; ++s) {
        const int k0 = s * 32 + kb * 8;
        short8 av = *(const short8*)&A_lds[mrow][k0];
        short8 bv = *(const short8*)(K_T + (size_t)fcol * 512 + k0);
        acc4 = __builtin_amdgcn_mfma_f32_16x16x32_bf16(av, bv, acc4, 0, 0, 0);
    }

    const float bb = bias[fcol];
#pragma unroll
    for (int r = 0; r < 4; ++r) {
        const int m = kb * 4 + r;
        out[(size_t)(node_base + m) * F + fcol] = acc4[r] + bb;
    }
}

// ---------------------------------------------------------------------------
extern "C" void kernel_launch(void* const* d_in, const int* in_sizes, int n_in,
                              void* d_out, int out_size, void* d_ws, size_t ws_size,
                              hipStream_t stream) {
    const float* nf   = (const float*)d_in[0];  // (N_IN, C)
    const float* ef   = (const float*)d_in[1];  // (T, E)
    const int*   idx  = (const int*)d_in[2];    // (E, 2) int32 on device
    const float* Kmat = (const float*)d_in[3];  // (T, C, F)
    const float* bias = (const float*)d_in[4];  // (F,)
    float*       out  = (float*)d_out;          // (N_OUT, F)

    char* ws = (char*)d_ws;
    unsigned short* nf_bf   = (unsigned short*)(ws + OFF_NFBF);
    unsigned short* K_T     = (unsigned short*)(ws + OFF_KT);
    int*            cnt     = (int*)(ws + OFF_CNT);  // becomes start[]
    int*            cursor  = (int*)(ws + OFF_CUR);
    int*            bsum    = (int*)(ws + OFF_BSUM);
    int*            isorted = (int*)(ws + OFF_ISRT);
    float*          wsorted = (float*)(ws + OFF_WSRT);

    const int nchunks = (N_OUT + 255) / 256;  // 196

    hipMemsetAsync(cnt, 0, (N_OUT + 1) * sizeof(int), stream);
    prep_kernel<<<NF_BLOCKS + KT_BLOCKS + HIST_BLOCKS, 256, 0, stream>>>(
        nf, Kmat, idx, nf_bf, K_T, cnt);
    scanA_kernel<<<nchunks, 256, 0, stream>>>(cnt, bsum);
    scanBC_kernel<<<nchunks, 256, 0, stream>>>(cnt, bsum, cursor);
    scatter_kernel<<<(E / 4 + 255) / 256, 256, 0, stream>>>(idx, ef, cursor, isorted, wsorted);
    aggregate_kernel<<<N_OUT / 16, 256, 0, stream>>>(
        nf_bf, K_T, cnt, isorted, wsorted, bias, out);
}